// Round 4
// baseline (260.183 us; speedup 1.0000x reference)
//
#include <hip/hip_runtime.h>

// Shapes (fixed by reference):
//   x : (32, 256, 64, 64) fp32   -> BS=32, C=256, HW=4096
//   w1: (32, 256)   b1: (32,)    -> HID=32
//   w2: (2, 512, 32) b2: (2,512) -> K=2, 2C=512
// out: (32, 256, 64, 64) fp32

#define BS   32
#define CCH  256
#define HW   4096
#define HID  32
#define KK   2

typedef float f4 __attribute__((ext_vector_type(4)));

// ---------------- Kernel 1: global average pool over (H,W) ----------------
// One block per (b,c) pair: 8192 blocks x 256 threads. 16 floats/thread via
// 4x float4 coalesced loads, shuffle reduce within wave64, LDS across waves.
// Normal (caching) loads: populates L2/IC with x for the apply pass.
__global__ __launch_bounds__(256) void pool_kernel(const float* __restrict__ x,
                                                   float* __restrict__ pooled) {
    const int bc = blockIdx.x;
    const float4* xp = (const float4*)(x + (size_t)bc * HW);
    const int t = threadIdx.x;
    float s = 0.f;
#pragma unroll
    for (int i = 0; i < 4; ++i) {
        float4 v = xp[t + i * 256];
        s += (v.x + v.y) + (v.z + v.w);
    }
#pragma unroll
    for (int off = 32; off > 0; off >>= 1)
        s += __shfl_down(s, off, 64);
    __shared__ float ws[4];
    if ((t & 63) == 0) ws[t >> 6] = s;
    __syncthreads();
    if (t == 0) {
        float tot = (ws[0] + ws[1]) + (ws[2] + ws[3]);
        pooled[bc] = tot * (1.0f / HW);
    }
}

// ---------------- Kernel 2: fused coef-MLP + apply + max over K -----------
// One block per (b,c) row: 8192 blocks x 256 threads.
// Each block redundantly computes the tiny MLP for its batch b, but only the
// 4 second-layer outputs it needs (k=0,1 x alpha/beta at channel c):
//   h = relu(pooled[b,:] @ w1.T + b1)            (32 units, 8 lanes each)
//   s_{k,sel} = w2[k, 2c+sel, :] . h + b2[...]   (4 dots of length 32)
//   a_k = init_a[k] + (2*sigmoid(s_{k,0})-1) ; b_k = init_b[k] + 0.5*(...)
// Cost: ~8.3K MACs/block vs 0.5 MB/block of memory traffic -> hidden.
// Removes the separate coef dispatch + one inter-kernel gap, and the A/Bc
// global round-trip.
__global__ __launch_bounds__(256) void apply_kernel(const float* __restrict__ x,
                                                    const float* __restrict__ pooled,
                                                    const float* __restrict__ w1,
                                                    const float* __restrict__ b1,
                                                    const float* __restrict__ w2,
                                                    const float* __restrict__ b2,
                                                    float* __restrict__ out) {
    const int bc = blockIdx.x;            // (b,c) row, 8192 total
    const int b = bc >> 8;
    const int c = bc & 255;
    const int t = threadIdx.x;

    __shared__ float pl[CCH];
    __shared__ float h[HID];
    __shared__ float cf[4];               // a0, b0, a1, b1

    pl[t] = pooled[b * CCH + t];          // 32 KB total, L2-hot
    __syncthreads();

    // ---- h = relu(pl @ w1.T + b1): 8 lanes per hidden unit ----
    {
        const int j  = t >> 3;            // hidden unit 0..31
        const int l8 = t & 7;             // lane within group of 8
        const float* w1r = w1 + j * CCH + l8 * 32;
        const float* plr = pl + l8 * 32;
        float s = 0.f;
#pragma unroll
        for (int c2 = 0; c2 < 32; ++c2) s += plr[c2] * w1r[c2];
#pragma unroll
        for (int off = 4; off > 0; off >>= 1)
            s += __shfl_down(s, off, 8);
        if (l8 == 0) h[j] = fmaxf(s + b1[j], 0.f);
    }
    __syncthreads();

    // ---- 4 second-layer outputs for this channel: groups of 8 lanes ----
    if (t < 32) {
        const int g   = t >> 3;           // 0..3 : (k, sel)
        const int k   = g >> 1;
        const int sel = g & 1;
        const int o   = 2 * c + sel;
        const int l8  = t & 7;
        const float* w2p = w2 + (size_t)(k * 2 * CCH + o) * HID + l8 * 4;
        float s = 0.f;
#pragma unroll
        for (int j = 0; j < 4; ++j) s += w2p[j] * h[l8 * 4 + j];
#pragma unroll
        for (int off = 4; off > 0; off >>= 1)
            s += __shfl_down(s, off, 8);
        if (l8 == 0) {
            s += b2[k * 2 * CCH + o];
            const float d = 2.f / (1.f + expf(-s)) - 1.f;   // 2*sigmoid-1
            const float initv = (k == 0) ? 1.f : 0.f;
            cf[g] = initv + (sel ? 0.5f : 1.0f) * d;  // LAMBDA_ALPHA=1, BETA=.5
        }
    }
    __syncthreads();

    const float a0  = cf[0];
    const float bb0 = cf[1];
    const float a1  = cf[2];
    const float bb1 = cf[3];

    // ---- apply + max over K, nt loads/stores ----
    const f4* xp = (const f4*)(x + (size_t)bc * HW);
    f4* op       = (f4*)(out + (size_t)bc * HW);
#pragma unroll
    for (int i = 0; i < 4; ++i) {
        const f4 v = __builtin_nontemporal_load(&xp[t + i * 256]);
        f4 r;
        r.x = fmaxf(v.x * a0 + bb0, v.x * a1 + bb1);
        r.y = fmaxf(v.y * a0 + bb0, v.y * a1 + bb1);
        r.z = fmaxf(v.z * a0 + bb0, v.z * a1 + bb1);
        r.w = fmaxf(v.w * a0 + bb0, v.w * a1 + bb1);
        __builtin_nontemporal_store(r, &op[t + i * 256]);
    }
}

extern "C" void kernel_launch(void* const* d_in, const int* in_sizes, int n_in,
                              void* d_out, int out_size, void* d_ws, size_t ws_size,
                              hipStream_t stream) {
    const float* x  = (const float*)d_in[0];
    const float* w1 = (const float*)d_in[1];
    const float* b1 = (const float*)d_in[2];
    const float* w2 = (const float*)d_in[3];
    const float* b2 = (const float*)d_in[4];
    float* out = (float*)d_out;

    // workspace layout (floats): pooled[8192]
    float* pooled = (float*)d_ws;

    pool_kernel<<<BS * CCH, 256, 0, stream>>>(x, pooled);
    apply_kernel<<<BS * CCH, 256, 0, stream>>>(x, pooled, w1, b1, w2, b2, out);
}